// Round 20
// baseline (15.833 us; speedup 1.0000x reference)
//
#include <hip/hip_runtime.h>

// GMP via MFMA: y[s] = sum_l (W[s-l,l] + a0[l]) * x[s-l], masked s<20.
// W[v,l] = sum_f Phi[v][f] * Theta[f][l]  (GEMM, K=64 padded)
//   Phi[v][4j+c] = q_{c+1}[v-j], j=0..10 valid    q_k = |x|^k
//   Theta[4*0+c][l] = a[c+1][9-l] (c<3), 0 for c=3
//   Theta[4(1+m)+c][l] = b[c][l][m], m=0..9;  f>=44 or l>=10 -> 0
//   bias a0[l] = a[0][9-l] added in the combine epilogue.
// Per wave: 128 samples, 9 position-groups of 16, 2 MFMA each.
// Coefficients enter via ONE B-fragment pair per wave (2 ds_read_b128)
// instead of the LDS-broadcast structure's 110 -- the structural win
// (18.2 -> 10.9us). Round-20 = round-13 champion restored verbatim;
// rounds 14-19 established the residual is ~3.4us LDS-throughput +
// ~7us phase-serialization latency (probe-measured), insensitive to
// reordering/dieting at this structure.

typedef short short8 __attribute__((ext_vector_type(8)));
typedef float f32x4 __attribute__((ext_vector_type(4)));

constexpr int S_FIXED = 16384;
constexpr int BLK = 256;          // 4 waves
constexpr int TILE = 512;         // samples per block (128 per wave)

__device__ __forceinline__ unsigned short bfc(float f) {
    union { float f; unsigned u; } v; v.f = f;
    const unsigned u = v.u;
    return (unsigned short)((u + 0x7FFFu + ((u >> 16) & 1u)) >> 16);
}

__device__ __forceinline__ short8 mk8(ushort4 lo, ushort4 hi) {
    union { ushort4 u[2]; short8 s; } x;
    x.u[0] = lo; x.u[1] = hi;
    return x.s;
}

__global__ __launch_bounds__(BLK) void gmp_mfma(
    const float* __restrict__ x,   // (B, S, 2)
    const float* __restrict__ a,   // (4, 10)
    const float* __restrict__ b,   // (4, 10, 10)
    float* __restrict__ out,       // (B, S, 2)
    int S)
{
    __shared__ alignas(16) unsigned short th[16][64];   // Theta[col=l][f] bf16
    __shared__ alignas(16) ushort4 qr[4][160];          // per-wave reversed quads
    __shared__ alignas(16) float wl[4][10][148];        // per-wave W[l][pos-idx]

    const int t = threadIdx.x;
    const int wid = t >> 6, lane = t & 63;
    const int m = lane & 15, h = lane >> 4;
    const int blocksPerRow = S / TILE;                  // 32
    const int brow = blockIdx.x / blocksPerRow;
    const int s0   = (blockIdx.x % blocksPerRow) * TILE;
    const int s0w  = s0 + 128 * wid;                    // this wave's samples
    const int vb   = s0w - 12;                          // position base

    // ---- Theta build (block-wide, 1024 entries) ----
    for (int idx = t; idx < 1024; idx += BLK) {
        const int col = idx >> 6, f = idx & 63;
        float v = 0.f;
        if (col < 10 && f < 44) {            // j <= 10 only
            const int j = f >> 2, c = f & 3;
            if (j == 0) { if (c < 3) v = a[(c + 1) * 10 + (9 - col)]; }
            else v = b[c * 100 + col * 10 + (j - 1)];
        }
        th[col][f] = bfc(v);
    }

    // ---- Q build: reversed quad table, qr[wid][i] = quads(vb + 143 - i) ----
    const float2* __restrict__ xr2 =
        reinterpret_cast<const float2*>(x) + (size_t)brow * S;
    for (int i = lane; i < 160; i += 64) {
        const int p = vb + 143 - i;
        float xre = 0.f, xim = 0.f;
        if (p >= 0 && p < S) { const float2 v = xr2[p]; xre = v.x; xim = v.y; }
        const float m2 = xre * xre + xim * xim;
        const float r  = __builtin_amdgcn_sqrtf(m2);
        ushort4 q;
        q.x = bfc(r); q.y = bfc(m2); q.z = bfc(m2 * r); q.w = bfc(m2 * m2);
        qr[wid][i] = q;
    }
    __syncthreads();   // th visible to all waves (qr is wave-private)

    // ---- B fragments (coefficients; once per wave) ----
    const short8 bfr0 = *reinterpret_cast<const short8*>(&th[m][8 * h]);
    const short8 bfr1 = *reinterpret_cast<const short8*>(&th[m][8 * h + 32]);

    // ---- MFMA: 9 groups of 16 positions; W -> LDS ----
    #pragma unroll
    for (int g = 0; g < 9; ++g) {
        // A row m -> position p_m = vb + 16g + m; k-chunk h -> quads at
        // p_m-2h, p_m-2h-1 (frag0) and p_m-2h-8, p_m-2h-9 (frag1).
        const int i1 = 143 - 16 * g - m + 2 * h;
        const short8 af0 = mk8(qr[wid][i1],     qr[wid][i1 + 1]);
        const short8 af1 = mk8(qr[wid][i1 + 8], qr[wid][i1 + 9]);
        f32x4 acc = {0.f, 0.f, 0.f, 0.f};
        acc = __builtin_amdgcn_mfma_f32_16x16x32_bf16(af0, bfr0, acc, 0, 0, 0);
        acc = __builtin_amdgcn_mfma_f32_16x16x32_bf16(af1, bfr1, acc, 0, 0, 0);
        // D: col = lane&15 (= l), rows (lane>>4)*4 + r (= position offset)
        if (m < 10)
            *reinterpret_cast<f32x4*>(&wl[wid][m][16 * g + 4 * h]) = acc;
    }

    // ---- combine epilogue: 2 samples per lane ----
    const int sa0 = s0w + 2 * lane;
    const float4* __restrict__ xr4 =
        reinterpret_cast<const float4*>(x) + (size_t)brow * (S / 2);
    float xf[24];   // complex window [sa0-10, sa0+2)
    {
        const int base4 = (sa0 - 10) / 2;   // sa0 even -> exact
        #pragma unroll
        for (int n = 0; n < 6; ++n) {
            int idx = base4 + n;
            if (idx < 0) idx = 0;           // garbage -> masked s<20 only
            const float4 f4 = xr4[idx];
            xf[4 * n + 0] = f4.x; xf[4 * n + 1] = f4.y;
            xf[4 * n + 2] = f4.z; xf[4 * n + 3] = f4.w;
        }
    }
    float yr0 = 0.f, yi0 = 0.f, yr1 = 0.f, yi1 = 0.f;
    #pragma unroll
    for (int l = 0; l < 10; ++l) {
        const float bl = a[9 - l];                       // a[0][9-l]
        const float w0 = wl[wid][l][2 * lane + 12 - l] + bl;
        const float w1 = wl[wid][l][2 * lane + 13 - l] + bl;
        const int wp = 10 - l;                           // window pos, j=0
        yr0 += w0 * xf[2 * wp];     yi0 += w0 * xf[2 * wp + 1];
        yr1 += w1 * xf[2 * wp + 2]; yi1 += w1 * xf[2 * wp + 3];
    }
    const bool k0 = sa0 >= 20, k1 = (sa0 + 1) >= 20;
    const float4 o = make_float4(k0 ? yr0 : 0.f, k0 ? yi0 : 0.f,
                                 k1 ? yr1 : 0.f, k1 ? yi1 : 0.f);
    reinterpret_cast<float4*>(out)[((size_t)brow * S + sa0) / 2] = o;
}

extern "C" void kernel_launch(void* const* d_in, const int* in_sizes, int n_in,
                              void* d_out, int out_size, void* d_ws, size_t ws_size,
                              hipStream_t stream) {
    const float* x = (const float*)d_in[0];
    const float* a = (const float*)d_in[1];
    const float* b = (const float*)d_in[2];
    // d_in[3] (c) is unused by the reference.
    float* out = (float*)d_out;

    const int S = S_FIXED;
    const int B = in_sizes[0] / (2 * S);
    const int nblocks = B * (S / TILE);

    gmp_mfma<<<dim3(nblocks), dim3(BLK), 0, stream>>>(x, a, b, out, S);
}

// Round 21
// 11.023 us; speedup vs baseline: 1.4364x; 1.4364x over previous
//
#include <hip/hip_runtime.h>

// GMP via MFMA: y[s] = sum_l (W[s-l,l] + a0[l]) * x[s-l], masked s<20.
// W[v,l] = sum_f Phi[v][f] * Theta[f][l]  (GEMM, K=64 padded)
//   Phi[v][4j+c] = q_{c+1}[v-j], j=0..10 valid    q_k = |x|^k
//   Theta[4*0+c][l] = a[c+1][9-l] (c<3), 0 for c=3
//   Theta[4(1+m)+c][l] = b[c][l][m], m=0..9;  f>=44 or l>=10 -> 0
//   bias a0[l] = a[0][9-l] added in the combine epilogue.
//
// Round-21: BARRIER-FREE variant of the r13 champion. The only reason
// for __syncthreads was publishing the LDS Theta tile; instead each
// lane gathers its 16 B-fragment coefficients directly from global
// (440-float region, L2/L1-hot; once per block). th removed, barrier
// removed -> all 4 waves fully independent (qr/wl wave-private;
// same-wave DS ops are in-order, the r18-probe-validated property).
// Tests whether the ~7.5us fixed cost (r18 decomposition) contains a
// barrier-lockstep slice. Output numerics bit-identical to r13.

typedef short short8 __attribute__((ext_vector_type(8)));
typedef float f32x4 __attribute__((ext_vector_type(4)));

constexpr int S_FIXED = 16384;
constexpr int BLK = 256;          // 4 waves
constexpr int TILE = 512;         // samples per block (128 per wave)

__device__ __forceinline__ unsigned short bfc(float f) {
    union { float f; unsigned u; } v; v.f = f;
    const unsigned u = v.u;
    return (unsigned short)((u + 0x7FFFu + ((u >> 16) & 1u)) >> 16);
}

__device__ __forceinline__ short8 mk8(ushort4 lo, ushort4 hi) {
    union { ushort4 u[2]; short8 s; } x;
    x.u[0] = lo; x.u[1] = hi;
    return x.s;
}

__global__ __launch_bounds__(BLK) void gmp_mfma(
    const float* __restrict__ x,   // (B, S, 2)
    const float* __restrict__ a,   // (4, 10)
    const float* __restrict__ b,   // (4, 10, 10)
    float* __restrict__ out,       // (B, S, 2)
    int S)
{
    __shared__ alignas(16) ushort4 qr[4][160];          // per-wave reversed quads
    __shared__ alignas(16) float wl[4][10][148];        // per-wave W[l][pos-idx]

    const int t = threadIdx.x;
    const int wid = t >> 6, lane = t & 63;
    const int m = lane & 15, h = lane >> 4;
    const int blocksPerRow = S / TILE;                  // 32
    const int brow = blockIdx.x / blocksPerRow;
    const int s0   = (blockIdx.x % blocksPerRow) * TILE;
    const int s0w  = s0 + 128 * wid;                    // this wave's samples
    const int vb   = s0w - 12;                          // position base

    // ---- B fragments via DIRECT GLOBAL GATHER (no th, no barrier) ----
    // lane (m,h) needs Theta[f][m] for f = 8h+e (bfr0) and 32+8h+e (bfr1).
    unsigned short b0e[8], b1e[8];
    #pragma unroll
    for (int e = 0; e < 8; ++e) {
        const int f0 = 8 * h + e;                  // 0..31 (< 44 always)
        const int j0 = f0 >> 2, c0 = f0 & 3;
        float v0 = 0.f;
        if (m < 10) {
            if (j0 == 0) { if (c0 < 3) v0 = a[(c0 + 1) * 10 + (9 - m)]; }
            else v0 = b[c0 * 100 + m * 10 + (j0 - 1)];
        }
        b0e[e] = bfc(v0);
        const int f1 = 32 + 8 * h + e;             // 32..63; valid iff < 44
        const int j1 = f1 >> 2, c1 = f1 & 3;       // j1 >= 8, never the a-row
        float v1 = 0.f;
        if (m < 10 && f1 < 44) v1 = b[c1 * 100 + m * 10 + (j1 - 1)];
        b1e[e] = bfc(v1);
    }
    short8 bfr0, bfr1;
    {
        union { unsigned short u[8]; short8 s; } p0, p1;
        #pragma unroll
        for (int e = 0; e < 8; ++e) { p0.u[e] = b0e[e]; p1.u[e] = b1e[e]; }
        bfr0 = p0.s; bfr1 = p1.s;
    }

    // ---- Q build: reversed quad table, qr[wid][i] = quads(vb + 143 - i) ----
    const float2* __restrict__ xr2 =
        reinterpret_cast<const float2*>(x) + (size_t)brow * S;
    for (int i = lane; i < 160; i += 64) {
        const int p = vb + 143 - i;
        float xre = 0.f, xim = 0.f;
        if (p >= 0 && p < S) { const float2 v = xr2[p]; xre = v.x; xim = v.y; }
        const float m2 = xre * xre + xim * xim;
        const float r  = __builtin_amdgcn_sqrtf(m2);
        ushort4 q;
        q.x = bfc(r); q.y = bfc(m2); q.z = bfc(m2 * r); q.w = bfc(m2 * m2);
        qr[wid][i] = q;
    }
    // NO barrier: qr/wl are wave-private; same-wave DS ops are in-order.

    // ---- MFMA: 9 groups of 16 positions; W -> LDS ----
    #pragma unroll
    for (int g = 0; g < 9; ++g) {
        // A row m -> position p_m = vb + 16g + m; k-chunk h -> quads at
        // p_m-2h, p_m-2h-1 (frag0) and p_m-2h-8, p_m-2h-9 (frag1).
        const int i1 = 143 - 16 * g - m + 2 * h;
        const short8 af0 = mk8(qr[wid][i1],     qr[wid][i1 + 1]);
        const short8 af1 = mk8(qr[wid][i1 + 8], qr[wid][i1 + 9]);
        f32x4 acc = {0.f, 0.f, 0.f, 0.f};
        acc = __builtin_amdgcn_mfma_f32_16x16x32_bf16(af0, bfr0, acc, 0, 0, 0);
        acc = __builtin_amdgcn_mfma_f32_16x16x32_bf16(af1, bfr1, acc, 0, 0, 0);
        // D: col = lane&15 (= l), rows (lane>>4)*4 + r (= position offset)
        if (m < 10)
            *reinterpret_cast<f32x4*>(&wl[wid][m][16 * g + 4 * h]) = acc;
    }

    // ---- combine epilogue: 2 samples per lane ----
    const int sa0 = s0w + 2 * lane;
    const float4* __restrict__ xr4 =
        reinterpret_cast<const float4*>(x) + (size_t)brow * (S / 2);
    float xf[24];   // complex window [sa0-10, sa0+2)
    {
        const int base4 = (sa0 - 10) / 2;   // sa0 even -> exact
        #pragma unroll
        for (int n = 0; n < 6; ++n) {
            int idx = base4 + n;
            if (idx < 0) idx = 0;           // garbage -> masked s<20 only
            const float4 f4 = xr4[idx];
            xf[4 * n + 0] = f4.x; xf[4 * n + 1] = f4.y;
            xf[4 * n + 2] = f4.z; xf[4 * n + 3] = f4.w;
        }
    }
    float yr0 = 0.f, yi0 = 0.f, yr1 = 0.f, yi1 = 0.f;
    #pragma unroll
    for (int l = 0; l < 10; ++l) {
        const float bl = a[9 - l];                       // a[0][9-l]
        const float w0 = wl[wid][l][2 * lane + 12 - l] + bl;
        const float w1 = wl[wid][l][2 * lane + 13 - l] + bl;
        const int wp = 10 - l;                           // window pos, j=0
        yr0 += w0 * xf[2 * wp];     yi0 += w0 * xf[2 * wp + 1];
        yr1 += w1 * xf[2 * wp + 2]; yi1 += w1 * xf[2 * wp + 3];
    }
    const bool k0 = sa0 >= 20, k1 = (sa0 + 1) >= 20;
    const float4 o = make_float4(k0 ? yr0 : 0.f, k0 ? yi0 : 0.f,
                                 k1 ? yr1 : 0.f, k1 ? yi1 : 0.f);
    reinterpret_cast<float4*>(out)[((size_t)brow * S + sa0) / 2] = o;
}

extern "C" void kernel_launch(void* const* d_in, const int* in_sizes, int n_in,
                              void* d_out, int out_size, void* d_ws, size_t ws_size,
                              hipStream_t stream) {
    const float* x = (const float*)d_in[0];
    const float* a = (const float*)d_in[1];
    const float* b = (const float*)d_in[2];
    // d_in[3] (c) is unused by the reference.
    float* out = (float*)d_out;

    const int S = S_FIXED;
    const int B = in_sizes[0] / (2 * S);
    const int nblocks = B * (S / TILE);

    gmp_mfma<<<dim3(nblocks), dim3(BLK), 0, stream>>>(x, a, b, out, S);
}